// Round 1
// baseline (909.068 us; speedup 1.0000x reference)
//
#include <hip/hip_runtime.h>
#include <math.h>

// Problem constants (from reference)
#define B_TOT     16384
#define NUM_CARDS 64
#define NUM_WORDS 50
#define LEN_EMB   128
#define LEN_DENSE 128

// One wave (64 threads) per batch element.
// Key algebraic reduction: Linear is per-card independent, so we gather the
// argmax card FIRST and do a single 128x128 matvec per batch row, instead of
// the reference's [64x128]@[128x128] per row. Cuts img read 536MB -> 8.4MB.
__global__ __launch_bounds__(64) void imaginarium_kernel(
    const float* __restrict__ img,   // [B, 64, 128]
    const float* __restrict__ txt,   // [B, 50, 128]
    const float* __restrict__ y,     // [B, 64]
    const float* __restrict__ W,     // [128, 128] row-major [e][d]
    const float* __restrict__ bias,  // [128]
    float* __restrict__ out)         // [B, 50]
{
  const int b    = blockIdx.x;
  const int lane = threadIdx.x;  // 0..63

  __shared__ float s_emb[LEN_EMB];
  __shared__ float s_leader[LEN_DENSE];
  __shared__ float s_logit[64];  // 50 used

  // ---- argmax over y[b, 0:64]; first occurrence wins (jnp.argmax semantics) ----
  float v  = y[(size_t)b * NUM_CARDS + lane];
  int   vi = lane;
  #pragma unroll
  for (int m = 1; m < 64; m <<= 1) {
    float ov = __shfl_xor(v,  m, 64);
    int   oi = __shfl_xor(vi, m, 64);
    if (ov > v || (ov == v && oi < vi)) { v = ov; vi = oi; }
  }
  const int idx = vi;  // all lanes agree

  // ---- gather leader embedding (128 floats = one contiguous 512B row) ----
  const float2* embp = (const float2*)(img + ((size_t)b * NUM_CARDS + idx) * LEN_EMB);
  float2 e2 = embp[lane];
  s_emb[2 * lane]     = e2.x;
  s_emb[2 * lane + 1] = e2.y;
  __syncthreads();  // single wave: compiles to waitcnt, cheap

  // ---- matvec: leader[e] = W[e,:]·emb + bias[e]; lane owns e=lane and e=lane+64 ----
  const float4* Wr0    = (const float4*)(W + (size_t)lane        * LEN_EMB);
  const float4* Wr1    = (const float4*)(W + (size_t)(lane + 64) * LEN_EMB);
  const float4* s_emb4 = (const float4*)s_emb;
  float acc0 = 0.f, acc1 = 0.f;
  #pragma unroll 8
  for (int d4 = 0; d4 < LEN_EMB / 4; ++d4) {
    float4 ev = s_emb4[d4];          // same addr all lanes -> LDS broadcast
    float4 w0 = Wr0[d4];             // W stays hot in L1/L2 (64 KB total)
    float4 w1 = Wr1[d4];
    acc0 += w0.x * ev.x + w0.y * ev.y + w0.z * ev.z + w0.w * ev.w;
    acc1 += w1.x * ev.x + w1.y * ev.y + w1.z * ev.z + w1.w * ev.w;
  }
  acc0 += bias[lane];
  acc1 += bias[lane + 64];
  s_leader[lane]      = acc0;
  s_leader[lane + 64] = acc1;

  // ---- ||leader|| ----
  float na2 = acc0 * acc0 + acc1 * acc1;
  #pragma unroll
  for (int m = 1; m < 64; m <<= 1) na2 += __shfl_xor(na2, m, 64);
  const float na = sqrtf(na2);
  __syncthreads();

  // ---- cosine logits: 2 words per iteration, one per half-wave ----
  // lanes 0-31 handle word 2*wp, lanes 32-63 handle word 2*wp+1.
  // Wave loads 2*512B = 1KB contiguous float4 per iteration (fully coalesced).
  const float4* txt4  = (const float4*)(txt + (size_t)b * NUM_WORDS * LEN_EMB);
  const float4* lead4 = (const float4*)s_leader;
  const int half = lane >> 5;
  const int l    = lane & 31;
  for (int wp = 0; wp < NUM_WORDS / 2; ++wp) {
    const int w = 2 * wp + half;
    float4 t  = txt4[(size_t)w * 32 + l];
    float4 ld = lead4[l];
    float dot = t.x * ld.x + t.y * ld.y + t.z * ld.z + t.w * ld.w;
    float nb2 = t.x * t.x  + t.y * t.y  + t.z * t.z  + t.w * t.w;
    #pragma unroll
    for (int m = 1; m <= 16; m <<= 1) {  // masks<32: stays within each half
      dot += __shfl_xor(dot, m, 64);
      nb2 += __shfl_xor(nb2, m, 64);
    }
    if (l == 0) {
      float denom = fmaxf(na * sqrtf(nb2), 1e-8f);
      s_logit[w] = dot / denom;
    }
  }
  __syncthreads();

  // ---- softmax over the 50 words ----
  float logit = (lane < NUM_WORDS) ? s_logit[lane] : -INFINITY;
  float mx = logit;
  #pragma unroll
  for (int m = 1; m < 64; m <<= 1) mx = fmaxf(mx, __shfl_xor(mx, m, 64));
  float ex = (lane < NUM_WORDS) ? expf(logit - mx) : 0.f;
  float sum = ex;
  #pragma unroll
  for (int m = 1; m < 64; m <<= 1) sum += __shfl_xor(sum, m, 64);
  if (lane < NUM_WORDS) out[(size_t)b * NUM_WORDS + lane] = ex / sum;
}

extern "C" void kernel_launch(void* const* d_in, const int* in_sizes, int n_in,
                              void* d_out, int out_size, void* d_ws, size_t ws_size,
                              hipStream_t stream) {
  const float* img  = (const float*)d_in[0];  // x_img_dense [B,64,128]
  const float* txt  = (const float*)d_in[1];  // x_txt_dense [B,50,128]
  const float* y    = (const float*)d_in[2];  // y_what_card_leader_choose [B,64]
  const float* W    = (const float*)d_in[3];  // W_img1 [128,128]
  const float* bias = (const float*)d_in[4];  // b_img1 [128]
  float* out = (float*)d_out;                 // [B,50] float32

  imaginarium_kernel<<<B_TOT, 64, 0, stream>>>(img, txt, y, W, bias, out);
}

// Round 2
// 889.693 us; speedup vs baseline: 1.0218x; 1.0218x over previous
//
#include <hip/hip_runtime.h>
#include <math.h>

// Problem constants (from reference)
#define B_TOT     16384
#define NUM_CARDS 64
#define NUM_WORDS 50
#define LEN_EMB   128
#define LEN_DENSE 128
#define ROWS_PER_BLOCK 4   // 4 waves/block, one batch row per wave:
                           // lifts the 16-workgroup/CU cap from 16 to ~24+ waves/CU

// One wave (64 threads) per batch element, 4 rows per 256-thread block.
// Algebraic reduction: Linear is per-card independent -> gather argmax card
// FIRST, single 128x128 matvec per row (img read 536MB -> 8.4MB).
// R1: cosine loop unrolled x5 with software prefetch (5 loads in flight,
// 10 interleaved shuffle chains) + txt prefetch overlapping the prologue.
__global__ __launch_bounds__(256) void imaginarium_kernel(
    const float* __restrict__ img,   // [B, 64, 128]
    const float* __restrict__ txt,   // [B, 50, 128]
    const float* __restrict__ y,     // [B, 64]
    const float* __restrict__ W,     // [128, 128] row-major [e][d]
    const float* __restrict__ bias,  // [128]
    float* __restrict__ out)         // [B, 50]
{
  const int wid  = threadIdx.x >> 6;   // wave id within block, 0..3
  const int lane = threadIdx.x & 63;   // 0..63
  const int b    = blockIdx.x * ROWS_PER_BLOCK + wid;

  __shared__ float s_emb[ROWS_PER_BLOCK][LEN_EMB];
  __shared__ float s_leader[ROWS_PER_BLOCK][LEN_EMB];
  __shared__ float s_logit[ROWS_PER_BLOCK][64];  // 50 used

  const int half = lane >> 5;  // 0/1: which word of the pair
  const int l    = lane & 31;  // lane within half-wave

  // ---- prefetch first 5 word-pairs of txt (independent of the prologue
  //      chain below; these HBM loads fly while we do argmax+matvec) ----
  const float4* txt4 = (const float4*)(txt + (size_t)b * NUM_WORDS * LEN_EMB);
  float4 t[5];
  #pragma unroll
  for (int k = 0; k < 5; ++k)
    t[k] = txt4[(size_t)(2 * k + half) * 32 + l];

  // ---- argmax over y[b, 0:64]; first occurrence wins ----
  float v  = y[(size_t)b * NUM_CARDS + lane];
  int   vi = lane;
  #pragma unroll
  for (int m = 1; m < 64; m <<= 1) {
    float ov = __shfl_xor(v,  m, 64);
    int   oi = __shfl_xor(vi, m, 64);
    if (ov > v || (ov == v && oi < vi)) { v = ov; vi = oi; }
  }
  const int idx = vi;  // all lanes agree

  // ---- gather leader embedding (contiguous 512B row) ----
  const float2* embp = (const float2*)(img + ((size_t)b * NUM_CARDS + idx) * LEN_EMB);
  float2 e2 = embp[lane];
  s_emb[wid][2 * lane]     = e2.x;
  s_emb[wid][2 * lane + 1] = e2.y;
  __syncthreads();

  // ---- matvec: leader[e] = W[e,:]·emb + bias[e]; lane owns e=lane, e=lane+64 ----
  const float4* Wr0    = (const float4*)(W + (size_t)lane        * LEN_EMB);
  const float4* Wr1    = (const float4*)(W + (size_t)(lane + 64) * LEN_EMB);
  const float4* s_emb4 = (const float4*)&s_emb[wid][0];
  float acc0 = 0.f, acc1 = 0.f;
  #pragma unroll 8
  for (int d4 = 0; d4 < LEN_EMB / 4; ++d4) {
    float4 ev = s_emb4[d4];          // same addr all lanes -> LDS broadcast
    float4 w0 = Wr0[d4];             // W is 64KB: L2-resident across all blocks
    float4 w1 = Wr1[d4];
    acc0 += w0.x * ev.x + w0.y * ev.y + w0.z * ev.z + w0.w * ev.w;
    acc1 += w1.x * ev.x + w1.y * ev.y + w1.z * ev.z + w1.w * ev.w;
  }
  acc0 += bias[lane];
  acc1 += bias[lane + 64];
  s_leader[wid][lane]      = acc0;
  s_leader[wid][lane + 64] = acc1;

  // ---- ||leader|| ----
  float na2 = acc0 * acc0 + acc1 * acc1;
  #pragma unroll
  for (int m = 1; m < 64; m <<= 1) na2 += __shfl_xor(na2, m, 64);
  const float na = sqrtf(na2);
  __syncthreads();

  // ---- cosine logits: 2 words per unrolled slot (one per half-wave),
  //      5 slots per group -> 5 loads in flight + 10 parallel shuffle chains ----
  const float4* lead4 = (const float4*)&s_leader[wid][0];
  const float4 ld = lead4[l];  // loop-invariant
  #pragma unroll
  for (int g = 0; g < 5; ++g) {
    float4 cur[5];
    #pragma unroll
    for (int k = 0; k < 5; ++k) cur[k] = t[k];
    if (g < 4) {  // prefetch next group while reducing this one
      #pragma unroll
      for (int k = 0; k < 5; ++k)
        t[k] = txt4[(size_t)(2 * ((g + 1) * 5 + k) + half) * 32 + l];
    }
    float dot[5], nb2[5];
    #pragma unroll
    for (int k = 0; k < 5; ++k) {
      dot[k] = cur[k].x * ld.x + cur[k].y * ld.y + cur[k].z * ld.z + cur[k].w * ld.w;
      nb2[k] = cur[k].x * cur[k].x + cur[k].y * cur[k].y + cur[k].z * cur[k].z + cur[k].w * cur[k].w;
    }
    #pragma unroll
    for (int m = 1; m <= 16; m <<= 1) {  // masks <32: stays within each half
      #pragma unroll
      for (int k = 0; k < 5; ++k) {
        dot[k] += __shfl_xor(dot[k], m, 64);
        nb2[k] += __shfl_xor(nb2[k], m, 64);
      }
    }
    if (l == 0) {
      #pragma unroll
      for (int k = 0; k < 5; ++k) {
        const int w = 2 * (g * 5 + k) + half;
        s_logit[wid][w] = dot[k] / fmaxf(na * sqrtf(nb2[k]), 1e-8f);
      }
    }
  }
  __syncthreads();

  // ---- softmax over the 50 words ----
  float logit = (lane < NUM_WORDS) ? s_logit[wid][lane] : -INFINITY;
  float mx = logit;
  #pragma unroll
  for (int m = 1; m < 64; m <<= 1) mx = fmaxf(mx, __shfl_xor(mx, m, 64));
  float ex = (lane < NUM_WORDS) ? expf(logit - mx) : 0.f;
  float sum = ex;
  #pragma unroll
  for (int m = 1; m < 64; m <<= 1) sum += __shfl_xor(sum, m, 64);
  if (lane < NUM_WORDS) out[(size_t)b * NUM_WORDS + lane] = ex / sum;
}

extern "C" void kernel_launch(void* const* d_in, const int* in_sizes, int n_in,
                              void* d_out, int out_size, void* d_ws, size_t ws_size,
                              hipStream_t stream) {
  const float* img  = (const float*)d_in[0];  // x_img_dense [B,64,128]
  const float* txt  = (const float*)d_in[1];  // x_txt_dense [B,50,128]
  const float* y    = (const float*)d_in[2];  // y_what_card_leader_choose [B,64]
  const float* W    = (const float*)d_in[3];  // W_img1 [128,128]
  const float* bias = (const float*)d_in[4];  // b_img1 [128]
  float* out = (float*)d_out;                 // [B,50] float32

  imaginarium_kernel<<<B_TOT / ROWS_PER_BLOCK, 256, 0, stream>>>(img, txt, y, W, bias, out);
}